// Round 10
// baseline (114.647 us; speedup 1.0000x reference)
//
#include <hip/hip_runtime.h>

// SiamFC cross-correlation: out[n,0,oh,ow] = sum_{c,i,j} x[n,c,oh+i,ow+j] * z[n,c,i,j]
// n=256, c=256, z=6x6, x=26x26, out=21x21.
//
// Round-10: barrier-FREE single-wave pipeline. Block = 64 threads (1 wave),
// 16 rounds x 2 channels, double-buffered LDS (11.4 KB -> all 8 blocks/CU
// co-resident, zero tail). global_load_lds(16B): 7 loads/round; the SAME wave
// consumes after s_waitcnt vmcnt(7) -- no s_barrier anywhere in the loop.
// Lanes: cc=bit0 (channel), g=bit1 (col half), t=bits2-4 (3-row tile, 7 used),
// h=bit5 (z rows 3h..3h+2). Per thread/round: 594 FMA per 49 ds_read_b64.
// Epilogue: shfl_xor lane-bit folds (cc, h), plain stores to ws; K2 folds splits.

#define OH 21
#define OW 21
#define XBUF 1352              // 2 ch * 676 floats
#define ZBUF 72                // 2 ch * 36 floats
#define BUFSTRIDE 1424         // XBUF + ZBUF (floats, 16B multiple)
#define NTHREADS 64
#define ROUNDS 16
#define SPLITS 8
#define WS_STRIDE 448          // per-(split,n) ws slot (floats)

typedef __attribute__((address_space(3))) unsigned int lds_u32_t;
typedef __attribute__((address_space(1))) const unsigned int glb_u32_t;

__device__ __forceinline__ void gload16(const void* g, void* l) {
    __builtin_amdgcn_global_load_lds((glb_u32_t*)g, (lds_u32_t*)l, 16, 0, 0);
}

__global__ __launch_bounds__(NTHREADS, 2)
void siamfc_xcorr_part(const float* __restrict__ z, const float* __restrict__ x,
                       float* __restrict__ ws) {
    __shared__ __align__(16) float lds[2 * BUFSTRIDE];   // 11392 B

    const int tid = threadIdx.x;        // == lane (1 wave)
    const int bid = blockIdx.x;
    const int n     = bid >> 3;
    const int split = bid & 7;
    const int cb0   = split * 32;       // 32 channels per block

    const int cc = tid & 1;             // channel within round
    const int g  = (tid >> 1) & 1;      // col half: cols 10g + o
    const int t  = (tid >> 2) & 7;      // 3-row tile, t==7 idle in compute
    const int h  = tid >> 5;            // z rows 3h..3h+2
    const bool active = (t < 7);

    const float4* xg4 = (const float4*)x + (size_t)n * (256 * 169);
    const float4* zg4 = (const float4*)z + (size_t)n * (256 * 9);

    // 7 global_load_lds per round: 5 full x + masked x tail + masked z
    auto issue = [&](int r, int b) {
        const float4* xsrc = xg4 + (size_t)(cb0 + 2 * r) * 169;  // 338 quads
        const float4* zsrc = zg4 + (size_t)(cb0 + 2 * r) * 9;    // 18 quads
        float* xb = lds + b * BUFSTRIDE;
        float* zb = xb + XBUF;
        #pragma unroll
        for (int k = 0; k < 5; ++k)                      // quads k*64 + lane
            gload16(xsrc + k * 64 + tid, xb + (size_t)(k * 64) * 4);
        if (tid < 18) {
            gload16(xsrc + 320 + tid, xb + (size_t)320 * 4);  // quads 320..337
            gload16(zsrc + tid, zb);                          // quads 0..17
        }
    };

    float acc[33];
    #pragma unroll
    for (int v = 0; v < 33; ++v) acc[v] = 0.f;

    issue(0, 0);

    #pragma unroll 1
    for (int r = 0; r < ROUNDS; ++r) {
        if (r < ROUNDS - 1) {
            issue(r + 1, (r + 1) & 1);
            asm volatile("s_waitcnt vmcnt(7)" ::: "memory");  // round-r DMA done
        } else {
            asm volatile("s_waitcnt vmcnt(0)" ::: "memory");
        }
        // same-wave consumption: no barrier needed

        if (active) {
            const float* xb = lds + (r & 1) * BUFSTRIDE;
            const float* zb = xb + XBUF;
            // z rows 3h..3h+2 of channel cc: 9 float2 broadcasts
            float zv[3][6];
            const float2* zp = (const float2*)(zb + cc * 36 + h * 18);
            #pragma unroll
            for (int e = 0; e < 9; ++e) {
                float2 q = zp[e];
                zv[e / 3][2 * (e % 3)]     = q.x;
                zv[e / 3][2 * (e % 3) + 1] = q.y;
            }
            const float* xcb = xb + cc * 676;
            #pragma unroll
            for (int m = 0; m < 5; ++m) {                // x rows 3t+3h+m (<=25)
                const int row = 3 * t + 3 * h + m;
                const float2* rp = (const float2*)xcb + 13 * row + 5 * g;
                float xr[16];                            // row floats 10g..10g+15
                #pragma unroll
                for (int s = 0; s < 8; ++s) {
                    float2 q = rp[s];
                    xr[2 * s] = q.x; xr[2 * s + 1] = q.y;
                }
                #pragma unroll
                for (int zr = 0; zr < 3; ++zr) {
                    const int a = m - zr;                // output row 3t+a
                    if (a >= 0 && a < 3) {
                        #pragma unroll
                        for (int j = 0; j < 6; ++j)
                            #pragma unroll
                            for (int o = 0; o < 11; ++o) // out col 10g+o
                                acc[a * 11 + o] = fmaf(zv[zr][j], xr[o + j], acc[a * 11 + o]);
                    }
                }
            }
        }
    }

    // ---- fold cc (lane bit 0) and h (lane bit 5) in-wave; partners share t,g
    #pragma unroll
    for (int v = 0; v < 33; ++v) {
        acc[v] += __shfl_xor(acc[v], 1, 64);
        acc[v] += __shfl_xor(acc[v], 32, 64);
    }
    // ---- plain store of this split's 441 partials (no atomics, no memset)
    if (active && cc == 0 && h == 0) {
        float* wp = ws + (size_t)(split * 256 + n) * WS_STRIDE;
        #pragma unroll
        for (int a = 0; a < 3; ++a) {
            const int row = 3 * t + a;
            for (int o = g; o < 11; ++o) {       // g=1 skips o=0 (col-10 dup)
                const int col = 10 * g + o;
                wp[row * OW + col] = acc[a * 11 + o];
            }
        }
    }
}

__global__ __launch_bounds__(WS_STRIDE, 4)
void siamfc_reduce(const float* __restrict__ ws, float* __restrict__ out) {
    const int n = blockIdx.x;
    const int o = threadIdx.x;
    if (o >= OH * OW) return;
    float s = 0.f;
    #pragma unroll
    for (int sp = 0; sp < SPLITS; ++sp)
        s += ws[(size_t)(sp * 256 + n) * WS_STRIDE + o];
    out[(size_t)n * (OH * OW) + o] = s;
}

extern "C" void kernel_launch(void* const* d_in, const int* in_sizes, int n_in,
                              void* d_out, int out_size, void* d_ws, size_t ws_size,
                              hipStream_t stream) {
    const float* z = (const float*)d_in[0];
    const float* x = (const float*)d_in[1];
    float* out = (float*)d_out;
    float* ws  = (float*)d_ws;
    siamfc_xcorr_part<<<dim3(256 * SPLITS), dim3(NTHREADS), 0, stream>>>(z, x, ws);
    siamfc_reduce<<<dim3(256), dim3(WS_STRIDE), 0, stream>>>(ws, out);
}

// Round 11
// 54.216 us; speedup vs baseline: 2.1146x; 2.1146x over previous
//
#include <hip/hip_runtime.h>

// SiamFC cross-correlation: out[n,0,oh,ow] = sum_{c,i,j} x[n,c,oh+i,ow+j] * z[n,c,i,j]
// n=256, c=256, z=6x6, x=26x26, out=21x21.
//
// Round-11 = Round-9 core (128 thr / 2 waves, CCON=4, global_load_lds(16B)
// double-buffered, counted s_waitcnt vmcnt(7) + raw s_barrier, shfl+LDS
// reduction, ws + tiny fold kernel) with the residency phase-tail removed:
// 6 splits/sample {44,44,44,44,40,40} channels -> grid 1536 = exactly the
// 6 resident blocks/CU (LDS 24576 B). 44=4*11, 40=4*10 rounds, no masking.

#define OH 21
#define OW 21
#define XBUF 2704              // 4 ch * 676 floats
#define ZBUF 144               // 4 ch * 36 floats
#define BUFSTRIDE 2848         // XBUF + ZBUF (floats, 16B multiple)
#define NTHREADS 128
#define NSPLITS 6
#define SLOT 36                // partial slot stride (floats)
#define WS_STRIDE 448          // per-(split,n) ws slot (floats)

typedef __attribute__((address_space(3))) unsigned int lds_u32_t;
typedef __attribute__((address_space(1))) const unsigned int glb_u32_t;

__device__ __forceinline__ void gload16(const void* g, void* l) {
    __builtin_amdgcn_global_load_lds((glb_u32_t*)g, (lds_u32_t*)l, 16, 0, 0);
}

__global__ __launch_bounds__(NTHREADS, 3)
void siamfc_xcorr_part(const float* __restrict__ z, const float* __restrict__ x,
                       float* __restrict__ ws) {
    __shared__ __align__(16) float lds[2 * BUFSTRIDE];

    const int tid  = threadIdx.x;
    const int lane = tid & 63;
    const int w    = tid >> 6;          // wave id == h
    const int bid  = blockIdx.x;
    const int n     = bid / NSPLITS;
    const int split = bid - n * NSPLITS;
    // splits 0-3: 44 channels (11 rounds); splits 4-5: 40 channels (10 rounds)
    const int cb0    = (split < 4) ? 44 * split : 176 + 40 * (split - 4);
    const int nround = (split < 4) ? 11 : 10;

    const int cc = tid & 3;
    const int g  = (tid >> 2) & 1;      // col half: cols 10g + o
    const int t  = (tid >> 3) & 7;      // 0..7, t==7 idle in compute
    const int h  = w;
    const bool active = (t < 7);

    const float4* xg4 = (const float4*)x + (size_t)n * (256 * 169);
    const float4* zg4 = (const float4*)z + (size_t)n * (256 * 9);

    // issue the 7 per-wave global_load_lds for round r into buffer b
    auto issue = [&](int r, int b) {
        const float4* xsrc = xg4 + (size_t)(cb0 + 4 * r) * 169;  // 676 quads
        const float4* zsrc = zg4 + (size_t)(cb0 + 4 * r) * 9;    // 36 quads
        float* xb = lds + b * BUFSTRIDE;
        float* zb = xb + XBUF;
        #pragma unroll
        for (int k = 0; k < 5; ++k)                      // quads k*128 + tid
            gload16(xsrc + k * 128 + tid, xb + (size_t)(k * 128 + w * 64) * 4);
        if (lane < 18) {                                 // x quads 640..675
            gload16(xsrc + 640 + w * 18 + lane, xb + (size_t)(640 + w * 18) * 4);
            // z quads 0..35
            gload16(zsrc + w * 18 + lane, zb + (size_t)(w * 18) * 4);
        }
    };

    float acc[33];
    #pragma unroll
    for (int v = 0; v < 33; ++v) acc[v] = 0.f;

    issue(0, 0);

    #pragma unroll 1
    for (int r = 0; r < nround; ++r) {
        if (r + 1 < nround) {
            issue(r + 1, (r + 1) & 1);
            asm volatile("s_waitcnt vmcnt(7)" ::: "memory");  // round-r loads done
        } else {
            asm volatile("s_waitcnt vmcnt(0)" ::: "memory");
        }
        __builtin_amdgcn_s_barrier();
        asm volatile("" ::: "memory");

        if (active) {
            const float* xb = lds + (r & 1) * BUFSTRIDE;
            const float* zb = xb + XBUF;
            // z rows 3h..3h+2 of channel cc: 9 float2 broadcasts
            float zv[3][6];
            const float2* zp = (const float2*)(zb + cc * 36 + h * 18);
            #pragma unroll
            for (int e = 0; e < 9; ++e) {
                float2 q = zp[e];
                zv[e / 3][2 * (e % 3)]     = q.x;
                zv[e / 3][2 * (e % 3) + 1] = q.y;
            }
            const float* xcb = xb + cc * 676;
            #pragma unroll
            for (int m = 0; m < 5; ++m) {                // x rows 3t+3h+m
                const int row = 3 * t + 3 * h + m;       // <= 25
                const float2* rp = (const float2*)xcb + 13 * row + 5 * g;
                float xr[16];                            // row floats 10g..10g+15
                #pragma unroll
                for (int s = 0; s < 8; ++s) {
                    float2 q = rp[s];
                    xr[2 * s] = q.x; xr[2 * s + 1] = q.y;
                }
                #pragma unroll
                for (int zr = 0; zr < 3; ++zr) {
                    const int a = m - zr;                // output row 3t+a
                    if (a >= 0 && a < 3) {
                        #pragma unroll
                        for (int j = 0; j < 6; ++j)
                            #pragma unroll
                            for (int o = 0; o < 11; ++o) // out col 10g+o
                                acc[a * 11 + o] = fmaf(zv[zr][j], xr[o + j], acc[a * 11 + o]);
                    }
                }
            }
        }
        __builtin_amdgcn_s_barrier();
        asm volatile("" ::: "memory");
    }

    // ---- reduce: shfl_xor across cc (lane bits 0,1), LDS slots across h
    #pragma unroll
    for (int v = 0; v < 33; ++v) {
        acc[v] += __shfl_xor(acc[v], 1, 64);
        acc[v] += __shfl_xor(acc[v], 2, 64);
    }
    if (active && cc == 0) {
        float* wsl = lds + (size_t)(h * 14 + t * 2 + g) * SLOT;
        #pragma unroll
        for (int v = 0; v < 33; ++v) wsl[v] = acc[v];
    }
    __syncthreads();

    // ---- plain store of this split's 441 partials (no atomics, no memset)
    float* wp = ws + (size_t)(split * 256 + n) * WS_STRIDE;
    for (int o = tid; o < OH * OW; o += NTHREADS) {
        int row = o / OW, c = o - row * OW;
        int tt = row / 3, a = row - tt * 3;
        int gg = (c >= 11) ? 1 : 0;
        int vi = a * 11 + (c - 10 * gg);
        wp[o] = lds[(      tt * 2 + gg) * SLOT + vi]
              + lds[(14 +  tt * 2 + gg) * SLOT + vi];
    }
}

__global__ __launch_bounds__(WS_STRIDE, 4)
void siamfc_reduce(const float* __restrict__ ws, float* __restrict__ out) {
    const int n = blockIdx.x;
    const int o = threadIdx.x;
    if (o >= OH * OW) return;
    float s = 0.f;
    #pragma unroll
    for (int sp = 0; sp < NSPLITS; ++sp)
        s += ws[(size_t)(sp * 256 + n) * WS_STRIDE + o];
    out[(size_t)n * (OH * OW) + o] = s;
}

extern "C" void kernel_launch(void* const* d_in, const int* in_sizes, int n_in,
                              void* d_out, int out_size, void* d_ws, size_t ws_size,
                              hipStream_t stream) {
    const float* z = (const float*)d_in[0];
    const float* x = (const float*)d_in[1];
    float* out = (float*)d_out;
    float* wsp = (float*)d_ws;
    siamfc_xcorr_part<<<dim3(256 * NSPLITS), dim3(NTHREADS), 0, stream>>>(z, x, wsp);
    siamfc_reduce<<<dim3(256), dim3(WS_STRIDE), 0, stream>>>(wsp, out);
}

// Round 12
// 52.860 us; speedup vs baseline: 2.1689x; 1.0257x over previous
//
#include <hip/hip_runtime.h>

// SiamFC cross-correlation: out[n,0,oh,ow] = sum_{c,i,j} x[n,c,oh+i,ow+j] * z[n,c,i,j]
// n=256, c=256, z=6x6, x=26x26, out=21x21.
//
// Round-12 = Round-11 core (128 thr / 2 waves, CCON=4, global_load_lds(16B)
// double-buffered, counted vmcnt + raw s_barrier, 6 splits {44,44,44,44,40,40},
// ws + fold kernel) with z moved OFF the LDS pipe:
//   - z is loaded global->registers (9 float2/thread/round, L2-resident,
//     issued BEFORE the next round's x-DMA so vmcnt(6) covers them)
//   - x DMA is 6 gloads/wave/round (z gload dropped) -> s_waitcnt vmcnt(6)
//   - LDS shrinks to 2*2704 floats = 21.6 KB (7-block capacity, 6 assigned)
// LDS reads drop 49 -> 40 b64 per thread-round (the critical pipe).

#define OH 21
#define OW 21
#define XBUF 2704              // 4 ch * 676 floats
#define BUFSTRIDE 2704
#define NTHREADS 128
#define NSPLITS 6
#define SLOT 36                // partial slot stride (floats)
#define WS_STRIDE 448          // per-(split,n) ws slot (floats)

typedef __attribute__((address_space(3))) unsigned int lds_u32_t;
typedef __attribute__((address_space(1))) const unsigned int glb_u32_t;

__device__ __forceinline__ void gload16(const void* g, void* l) {
    __builtin_amdgcn_global_load_lds((glb_u32_t*)g, (lds_u32_t*)l, 16, 0, 0);
}

__global__ __launch_bounds__(NTHREADS, 3)
void siamfc_xcorr_part(const float* __restrict__ z, const float* __restrict__ x,
                       float* __restrict__ ws) {
    __shared__ __align__(16) float lds[2 * BUFSTRIDE];   // 21632 B

    const int tid  = threadIdx.x;
    const int lane = tid & 63;
    const int w    = tid >> 6;          // wave id == h
    const int bid  = blockIdx.x;
    const int n     = bid / NSPLITS;
    const int split = bid - n * NSPLITS;
    // splits 0-3: 44 channels (11 rounds); splits 4-5: 40 channels (10 rounds)
    const int cb0    = (split < 4) ? 44 * split : 176 + 40 * (split - 4);
    const int nround = (split < 4) ? 11 : 10;

    const int cc = tid & 3;
    const int g  = (tid >> 2) & 1;      // col half: cols 10g + o
    const int t  = (tid >> 3) & 7;      // 0..7, t==7 idle in compute
    const int h  = w;
    const bool active = (t < 7);

    const float4* xg4 = (const float4*)x + (size_t)n * (256 * 169);
    const float2* zg2 = (const float2*)z + (size_t)n * (256 * 18);

    // 6 per-wave global_load_lds for round r into buffer b (x only)
    auto issue = [&](int r, int b) {
        const float4* xsrc = xg4 + (size_t)(cb0 + 4 * r) * 169;  // 676 quads
        float* xb = lds + b * BUFSTRIDE;
        #pragma unroll
        for (int k = 0; k < 5; ++k)                      // quads k*128 + tid
            gload16(xsrc + k * 128 + tid, xb + (size_t)(k * 128 + w * 64) * 4);
        if (lane < 18)                                   // x quads 640..675
            gload16(xsrc + 640 + w * 18 + lane, xb + (size_t)(640 + w * 18) * 4);
    };

    float acc[33];
    #pragma unroll
    for (int v = 0; v < 33; ++v) acc[v] = 0.f;

    issue(0, 0);

    #pragma unroll 1
    for (int r = 0; r < nround; ++r) {
        // ---- z for round r: global -> registers (BEFORE next G so vmcnt(6)
        //      forces them complete as well). All lanes load (t=7 harmless).
        float2 zq[9];
        {
            const float2* zp = zg2 + (size_t)(cb0 + 4 * r + cc) * 18 + 9 * h;
            #pragma unroll
            for (int e = 0; e < 9; ++e) zq[e] = zp[e];
        }
        if (r + 1 < nround) {
            issue(r + 1, (r + 1) & 1);
            asm volatile("s_waitcnt vmcnt(6)" ::: "memory");  // round-r x DMA + z regs done
        } else {
            asm volatile("s_waitcnt vmcnt(0)" ::: "memory");
        }
        __builtin_amdgcn_s_barrier();
        asm volatile("" ::: "memory");

        if (active) {
            const float* xb = lds + (r & 1) * BUFSTRIDE;
            float zv[3][6];
            #pragma unroll
            for (int e = 0; e < 9; ++e) {
                zv[e / 3][2 * (e % 3)]     = zq[e].x;
                zv[e / 3][2 * (e % 3) + 1] = zq[e].y;
            }
            const float* xcb = xb + cc * 676;
            #pragma unroll
            for (int m = 0; m < 5; ++m) {                // x rows 3t+3h+m
                const int row = 3 * t + 3 * h + m;       // <= 25
                const float2* rp = (const float2*)xcb + 13 * row + 5 * g;
                float xr[16];                            // row floats 10g..10g+15
                #pragma unroll
                for (int s = 0; s < 8; ++s) {
                    float2 q = rp[s];
                    xr[2 * s] = q.x; xr[2 * s + 1] = q.y;
                }
                #pragma unroll
                for (int zr = 0; zr < 3; ++zr) {
                    const int a = m - zr;                // output row 3t+a
                    if (a >= 0 && a < 3) {
                        #pragma unroll
                        for (int j = 0; j < 6; ++j)
                            #pragma unroll
                            for (int o = 0; o < 11; ++o) // out col 10g+o
                                acc[a * 11 + o] = fmaf(zv[zr][j], xr[o + j], acc[a * 11 + o]);
                    }
                }
            }
        }
        __builtin_amdgcn_s_barrier();
        asm volatile("" ::: "memory");
    }

    // ---- reduce: shfl_xor across cc (lane bits 0,1), LDS slots across h
    #pragma unroll
    for (int v = 0; v < 33; ++v) {
        acc[v] += __shfl_xor(acc[v], 1, 64);
        acc[v] += __shfl_xor(acc[v], 2, 64);
    }
    if (active && cc == 0) {
        float* wsl = lds + (size_t)(h * 14 + t * 2 + g) * SLOT;
        #pragma unroll
        for (int v = 0; v < 33; ++v) wsl[v] = acc[v];
    }
    __syncthreads();

    // ---- plain store of this split's 441 partials (no atomics, no memset)
    float* wp = ws + (size_t)(split * 256 + n) * WS_STRIDE;
    for (int o = tid; o < OH * OW; o += NTHREADS) {
        int row = o / OW, c = o - row * OW;
        int tt = row / 3, a = row - tt * 3;
        int gg = (c >= 11) ? 1 : 0;
        int vi = a * 11 + (c - 10 * gg);
        wp[o] = lds[(      tt * 2 + gg) * SLOT + vi]
              + lds[(14 +  tt * 2 + gg) * SLOT + vi];
    }
}

__global__ __launch_bounds__(WS_STRIDE, 4)
void siamfc_reduce(const float* __restrict__ ws, float* __restrict__ out) {
    const int n = blockIdx.x;
    const int o = threadIdx.x;
    if (o >= OH * OW) return;
    float s = 0.f;
    #pragma unroll
    for (int sp = 0; sp < NSPLITS; ++sp)
        s += ws[(size_t)(sp * 256 + n) * WS_STRIDE + o];
    out[(size_t)n * (OH * OW) + o] = s;
}

extern "C" void kernel_launch(void* const* d_in, const int* in_sizes, int n_in,
                              void* d_out, int out_size, void* d_ws, size_t ws_size,
                              hipStream_t stream) {
    const float* z = (const float*)d_in[0];
    const float* x = (const float*)d_in[1];
    float* out = (float*)d_out;
    float* wsp = (float*)d_ws;
    siamfc_xcorr_part<<<dim3(256 * NSPLITS), dim3(NTHREADS), 0, stream>>>(z, x, wsp);
    siamfc_reduce<<<dim3(256), dim3(WS_STRIDE), 0, stream>>>(wsp, out);
}